// Round 3
// baseline (2242.503 us; speedup 1.0000x reference)
//
#include <hip/hip_runtime.h>

// FFJORD CNF on MI355X. Transposed-MFMA design: every layer computed as
// H^T = W^T · X^T with v_mfma_f32_16x16x16_f16. For K=16 the C/D fragment
// layout (col=lane&15=sample, row=(lane>>4)*4+reg=feature) equals the
// B-operand layout, so layer outputs feed the next layer with only in-lane
// tanh + f32->f16 converts. Time column folded into bias: b_eff = b + t*W_row.
// Weights prepacked into MFMA A-fragment lane order in d_ws, copied to LDS.
//
// R2 fix: the FUNC lambda (capture-by-ref + float* out-param) failed to
// inline -> z/eps/kc lived in scratch -> 6.4 GB HBM traffic, VGPR_Count=84.
// Body is now pasted directly into the rolled stage loop; all array indices
// are compile-time so SROA keeps the whole state in registers.

typedef _Float16 h4 __attribute__((ext_vector_type(4)));
typedef float f4 __attribute__((ext_vector_type(4)));

#define MFMA16(A, B, C) __builtin_amdgcn_mfma_f32_16x16x16f16((A), (B), (C), 0, 0, 0)

__device__ __forceinline__ float fast_tanh(float x) {
  float e = __expf(2.0f * x);
  return 1.0f - 2.0f * __builtin_amdgcn_rcpf(e + 1.0f);
}

// ---------------- prepack: global weights -> MFMA fragment order in ws ----
// ws layout (bytes):
//   [0      .. 8192 )  w0 frags: 16 fragchunks x 64 lanes x h4   (8 KB)
//   [8192   .. 40960)  w1 frags: 64 fragchunks x 64 lanes x h4   (32 KB)
//   [40960  .. 49152)  w2 frags: 16 fragchunks x 64 lanes x h4   (8 KB)
//   [49152  .. 51456)  bias/time-row floats: bw[576]
//       bw[0:128]=b0  bw[128:256]=W0row32  bw[256:384]=b1 bw[384:512]=W1row128
//       bw[512:544]=b2 bw[544:576]=W2row128
__global__ void prepack_kernel(const float* __restrict__ W0, const float* __restrict__ b0,
                               const float* __restrict__ W1, const float* __restrict__ b1,
                               const float* __restrict__ W2, const float* __restrict__ b2,
                               char* __restrict__ ws) {
  h4* w0f = (h4*)(ws);
  h4* w1f = (h4*)(ws + 8192);
  h4* w2f = (h4*)(ws + 40960);
  float* bw = (float*)(ws + 49152);
  int tid = blockIdx.x * blockDim.x + threadIdx.x;
  int np = gridDim.x * blockDim.x;
  // A-fragment: A[m=f*16+(lane&15)][k=c*16+(lane>>4)*4+j] = W^T[m][k] = W[k][m]
  for (int e = tid; e < 1024; e += np) {
    int fc = e >> 6, lane = e & 63;
    int row = (fc >> 1) * 16 + (lane & 15);   // output feature (0..127)
    int kb = (fc & 1) * 16 + ((lane >> 4) << 2);
    h4 v;
#pragma unroll
    for (int j = 0; j < 4; j++) v[j] = (_Float16)W0[(kb + j) * 128 + row];
    w0f[e] = v;
  }
  for (int e = tid; e < 4096; e += np) {
    int fc = e >> 6, lane = e & 63;
    int row = (fc >> 3) * 16 + (lane & 15);
    int kb = (fc & 7) * 16 + ((lane >> 4) << 2);
    h4 v;
#pragma unroll
    for (int j = 0; j < 4; j++) v[j] = (_Float16)W1[(kb + j) * 128 + row];
    w1f[e] = v;
  }
  for (int e = tid; e < 1024; e += np) {
    int fc = e >> 6, lane = e & 63;
    int row = (fc >> 3) * 16 + (lane & 15);   // output feature (0..31)
    int kb = (fc & 7) * 16 + ((lane >> 4) << 2);
    h4 v;
#pragma unroll
    for (int j = 0; j < 4; j++) v[j] = (_Float16)W2[(kb + j) * 32 + row];
    w2f[e] = v;
  }
  for (int e = tid; e < 128; e += np) {
    bw[e] = b0[e];
    bw[128 + e] = W0[32 * 128 + e];
    bw[256 + e] = b1[e];
    bw[384 + e] = W1[128 * 128 + e];
  }
  for (int e = tid; e < 32; e += np) {
    bw[512 + e] = b2[e];
    bw[544 + e] = W2[128 * 32 + e];
  }
}

// ---------------- main kernel: 16 samples/wave, 4 waves/block --------------
__global__ __launch_bounds__(256, 3) void ffjord_kernel(
    const float* __restrict__ z1g, const float* __restrict__ epsg,
    const char* __restrict__ ws, float* __restrict__ out) {
  __shared__ h4 s_w0[1024];   // 8 KB
  __shared__ h4 s_w1[4096];   // 32 KB
  __shared__ h4 s_w2[1024];   // 8 KB
  __shared__ float s_bw[576]; // 2.25 KB

  {
    int t = threadIdx.x;
    const f4* s0 = (const f4*)(ws);
    const f4* s1 = (const f4*)(ws + 8192);
    const f4* s2 = (const f4*)(ws + 40960);
    const f4* s3 = (const f4*)(ws + 49152);
    f4* d0 = (f4*)s_w0;
    f4* d1 = (f4*)s_w1;
    f4* d2 = (f4*)s_w2;
    f4* d3 = (f4*)s_bw;
#pragma unroll
    for (int i = 0; i < 2; i++) d0[t + 256 * i] = s0[t + 256 * i];
#pragma unroll
    for (int i = 0; i < 8; i++) d1[t + 256 * i] = s1[t + 256 * i];
#pragma unroll
    for (int i = 0; i < 2; i++) d2[t + 256 * i] = s2[t + 256 * i];
    if (t < 144) d3[t] = s3[t];
  }
  __syncthreads();

  const int lane = threadIdx.x & 63;
  const int wv = threadIdx.x >> 6;
  const int sl = lane & 15;
  const int g4 = ((lane >> 4) << 2);
  const int sample = (blockIdx.x * 4 + wv) * 16 + sl;

  // per-lane state: features {c*16 + g4 + j} for c in {0,1}, j in 0..3
  float z[8], epsC[8];
  {
    const f4* zp = (const f4*)(z1g + sample * 32);
    f4 a = zp[g4 >> 2], b = zp[(16 + g4) >> 2];
#pragma unroll
    for (int j = 0; j < 4; j++) { z[j] = a[j]; z[4 + j] = b[j]; }
    const f4* ep = (const f4*)(epsg + sample * 32);
    f4 c = ep[g4 >> 2], d = ep[(16 + g4) >> 2];
#pragma unroll
    for (int j = 0; j < 4; j++) { epsC[j] = c[j]; epsC[4 + j] = d[j]; }
  }
  h4 hE0, hE1;
#pragma unroll
  for (int j = 0; j < 4; j++) { hE0[j] = (_Float16)epsC[j]; hE1[j] = (_Float16)epsC[4 + j]; }

  float ld = 0.0f;

  // RK4, reversed time: 5 steps, dt = -0.2
#pragma unroll 1
  for (int step = 0; step < 5; step++) {
    float t1 = 1.0f - 0.2f * (float)step;
    float kc[8], dk[8];
#pragma unroll
    for (int i = 0; i < 8; i++) { kc[i] = 0.0f; dk[i] = 0.0f; }
    float dl = 0.0f;
#pragma unroll 1
    for (int st = 0; st < 4; st++) {
      // stage input scale == stage t offset: {0, -0.1, -0.1, -0.2}
      float isc = (st == 0) ? 0.0f : ((st == 3) ? -0.2f : -0.1f);
      float wg = (st == 1 || st == 2) ? 2.0f : 1.0f;
      float t = t1 + isc;
      h4 hz0, hz1;
#pragma unroll
      for (int j = 0; j < 4; j++) {
        hz0[j] = (_Float16)(z[j] + isc * kc[j]);
        hz1[j] = (_Float16)(z[4 + j] + isc * kc[4 + j]);
      }

      // ---- f(z,t): layer 1 (32 -> 128, tanh) primal + tangent ----
      h4 hh[8], hd[8];
#pragma unroll
      for (int f = 0; f < 8; f++) {
        f4 bb = *(const f4*)&s_bw[f * 16 + g4];
        f4 bt = *(const f4*)&s_bw[128 + f * 16 + g4];
        f4 ap, at;
#pragma unroll
        for (int j = 0; j < 4; j++) { ap[j] = bb[j] + t * bt[j]; at[j] = 0.0f; }
        h4 A0 = s_w0[(f * 2 + 0) * 64 + lane];
        h4 A1 = s_w0[(f * 2 + 1) * 64 + lane];
        ap = MFMA16(A0, hz0, ap);
        ap = MFMA16(A1, hz1, ap);
        at = MFMA16(A0, hE0, at);
        at = MFMA16(A1, hE1, at);
#pragma unroll
        for (int j = 0; j < 4; j++) {
          float th = fast_tanh(ap[j]);
          float dv = (1.0f - th * th) * at[j];
          hh[f][j] = (_Float16)th;
          hd[f][j] = (_Float16)dv;
        }
      }

      // ---- layer 2 (128 -> 128, tanh) ----
      h4 g1[8], gd[8];
#pragma unroll
      for (int f = 0; f < 8; f++) {
        f4 bb = *(const f4*)&s_bw[256 + f * 16 + g4];
        f4 bt = *(const f4*)&s_bw[384 + f * 16 + g4];
        f4 ap, at;
#pragma unroll
        for (int j = 0; j < 4; j++) { ap[j] = bb[j] + t * bt[j]; at[j] = 0.0f; }
#pragma unroll
        for (int c = 0; c < 8; c++) {
          h4 A = s_w1[(f * 8 + c) * 64 + lane];
          ap = MFMA16(A, hh[c], ap);
          at = MFMA16(A, hd[c], at);
        }
#pragma unroll
        for (int j = 0; j < 4; j++) {
          float th = fast_tanh(ap[j]);
          float dv = (1.0f - th * th) * at[j];
          g1[f][j] = (_Float16)th;
          gd[f][j] = (_Float16)dv;
        }
      }

      // ---- layer 3 (128 -> 32, linear) + Hutchinson partial ----
      float lp = 0.0f;
#pragma unroll
      for (int f = 0; f < 2; f++) {
        f4 bb = *(const f4*)&s_bw[512 + f * 16 + g4];
        f4 bt = *(const f4*)&s_bw[544 + f * 16 + g4];
        f4 ap, at;
#pragma unroll
        for (int j = 0; j < 4; j++) { ap[j] = bb[j] + t * bt[j]; at[j] = 0.0f; }
#pragma unroll
        for (int c = 0; c < 8; c++) {
          h4 A = s_w2[(f * 8 + c) * 64 + lane];
          ap = MFMA16(A, g1[c], ap);
          at = MFMA16(A, gd[c], at);
        }
#pragma unroll
        for (int j = 0; j < 4; j++) {
          kc[f * 4 + j] = ap[j];
          lp += epsC[f * 4 + j] * at[j];
        }
      }
      lp += __shfl_xor(lp, 16, 64);
      lp += __shfl_xor(lp, 32, 64);

#pragma unroll
      for (int i = 0; i < 8; i++) dk[i] += wg * kc[i];
      dl += wg * lp;
    }
#pragma unroll
    for (int i = 0; i < 8; i++) z[i] += (-0.2f / 6.0f) * dk[i];
    ld += (0.2f / 6.0f) * dl;   // ld -= dlogpz, dlogpz = dl*(dt/6), dt=-0.2
  }

  {
    f4* op = (f4*)(out + sample * 32);
    f4 a, b;
#pragma unroll
    for (int j = 0; j < 4; j++) { a[j] = z[j]; b[j] = z[4 + j]; }
    op[g4 >> 2] = a;
    op[(16 + g4) >> 2] = b;
    if (lane < 16) out[131072 * 32 + sample] = ld;
  }
}

extern "C" void kernel_launch(void* const* d_in, const int* in_sizes, int n_in,
                              void* d_out, int out_size, void* d_ws, size_t ws_size,
                              hipStream_t stream) {
  (void)in_sizes; (void)n_in; (void)out_size; (void)ws_size;
  const float* z1 = (const float*)d_in[0];
  const float* eps = (const float*)d_in[1];
  const float* W0 = (const float*)d_in[2];
  const float* b0 = (const float*)d_in[3];
  const float* W1 = (const float*)d_in[4];
  const float* b1 = (const float*)d_in[5];
  const float* W2 = (const float*)d_in[6];
  const float* b2 = (const float*)d_in[7];
  float* out = (float*)d_out;

  prepack_kernel<<<16, 256, 0, stream>>>(W0, b0, W1, b1, W2, b2, (char*)d_ws);
  ffjord_kernel<<<131072 / 64, 256, 0, stream>>>(z1, eps, (const char*)d_ws, out);
}

// Round 4
// 1276.778 us; speedup vs baseline: 1.7564x; 1.7564x over previous
//
#include <hip/hip_runtime.h>

// FFJORD CNF on MI355X. Transposed-MFMA design: every layer computed as
// H^T = W^T · X^T with v_mfma_f32_16x16x16_f16. For K=16 the C/D fragment
// layout (col=lane&15=sample, row=(lane>>4)*4+reg=feature) equals the
// B-operand layout, so layer outputs feed the next layer with only in-lane
// tanh + f32->f16 converts. Time column folded into bias: b_eff = b + t*W_row.
//
// R3 post-mortem: VGPR=84 + 7 GB HBM in BOTH array versions -> the h4/f4
// LOCAL ARRAYS were demoted to scratch (guide rule #20). This version has
// ZERO local arrays: all state is individually named vector registers,
// layers macro-expanded with compile-time LDS offsets.

typedef _Float16 h4 __attribute__((ext_vector_type(4)));
typedef float f4 __attribute__((ext_vector_type(4)));

#define MFMA16(A, B, C) __builtin_amdgcn_mfma_f32_16x16x16f16((A), (B), (C), 0, 0, 0)

__device__ __forceinline__ float fast_tanh(float x) {
  float e = __expf(2.0f * x);
  return 1.0f - 2.0f * __builtin_amdgcn_rcpf(e + 1.0f);
}

// ---------------- prepack: global weights -> MFMA fragment order in ws ----
// ws layout (bytes):
//   [0      .. 8192 )  w0 frags: 16 fragchunks x 64 lanes x h4   (8 KB)
//   [8192   .. 40960)  w1 frags: 64 fragchunks x 64 lanes x h4   (32 KB)
//   [40960  .. 49152)  w2 frags: 16 fragchunks x 64 lanes x h4   (8 KB)
//   [49152  .. 51456)  bias/time-row floats: bw[576]
//       bw[0:128]=b0  bw[128:256]=W0row32  bw[256:384]=b1 bw[384:512]=W1row128
//       bw[512:544]=b2 bw[544:576]=W2row128
__global__ void prepack_kernel(const float* __restrict__ W0, const float* __restrict__ b0,
                               const float* __restrict__ W1, const float* __restrict__ b1,
                               const float* __restrict__ W2, const float* __restrict__ b2,
                               char* __restrict__ ws) {
  h4* w0f = (h4*)(ws);
  h4* w1f = (h4*)(ws + 8192);
  h4* w2f = (h4*)(ws + 40960);
  float* bw = (float*)(ws + 49152);
  int tid = blockIdx.x * blockDim.x + threadIdx.x;
  int np = gridDim.x * blockDim.x;
  // A-fragment: A[m=f*16+(lane&15)][k=c*16+(lane>>4)*4+j] = W^T[m][k] = W[k][m]
  for (int e = tid; e < 1024; e += np) {
    int fc = e >> 6, lane = e & 63;
    int row = (fc >> 1) * 16 + (lane & 15);   // output feature (0..127)
    int kb = (fc & 1) * 16 + ((lane >> 4) << 2);
    h4 v;
#pragma unroll
    for (int j = 0; j < 4; j++) v[j] = (_Float16)W0[(kb + j) * 128 + row];
    w0f[e] = v;
  }
  for (int e = tid; e < 4096; e += np) {
    int fc = e >> 6, lane = e & 63;
    int row = (fc >> 3) * 16 + (lane & 15);
    int kb = (fc & 7) * 16 + ((lane >> 4) << 2);
    h4 v;
#pragma unroll
    for (int j = 0; j < 4; j++) v[j] = (_Float16)W1[(kb + j) * 128 + row];
    w1f[e] = v;
  }
  for (int e = tid; e < 1024; e += np) {
    int fc = e >> 6, lane = e & 63;
    int row = (fc >> 3) * 16 + (lane & 15);   // output feature (0..31)
    int kb = (fc & 7) * 16 + ((lane >> 4) << 2);
    h4 v;
#pragma unroll
    for (int j = 0; j < 4; j++) v[j] = (_Float16)W2[(kb + j) * 32 + row];
    w2f[e] = v;
  }
  for (int e = tid; e < 128; e += np) {
    bw[e] = b0[e];
    bw[128 + e] = W0[32 * 128 + e];
    bw[256 + e] = b1[e];
    bw[384 + e] = W1[128 * 128 + e];
  }
  for (int e = tid; e < 32; e += np) {
    bw[512 + e] = b2[e];
    bw[544 + e] = W2[128 * 32 + e];
  }
}

// ---- per-layer macros: all state in NAMED registers, offsets constant ----
#define TANHPACK(ap, at, HH, HD)                                              \
  {                                                                           \
    float th0 = fast_tanh((ap).x), th1 = fast_tanh((ap).y);                   \
    float th2 = fast_tanh((ap).z), th3 = fast_tanh((ap).w);                   \
    HH = (h4){(_Float16)th0, (_Float16)th1, (_Float16)th2, (_Float16)th3};    \
    HD = (h4){(_Float16)((1.0f - th0 * th0) * (at).x),                        \
              (_Float16)((1.0f - th1 * th1) * (at).y),                        \
              (_Float16)((1.0f - th2 * th2) * (at).z),                        \
              (_Float16)((1.0f - th3 * th3) * (at).w)};                       \
  }

#define L1(F, HH, HD)                                                         \
  {                                                                           \
    f4 bb = *(const f4*)&s_bw[(F) * 16 + g4];                                 \
    f4 bt = *(const f4*)&s_bw[128 + (F) * 16 + g4];                           \
    f4 ap = bb + t * bt;                                                      \
    f4 at = {0.0f, 0.0f, 0.0f, 0.0f};                                         \
    h4 A0 = s_w0[((F) * 2 + 0) * 64 + lane];                                  \
    h4 A1 = s_w0[((F) * 2 + 1) * 64 + lane];                                  \
    ap = MFMA16(A0, hz0, ap);                                                 \
    ap = MFMA16(A1, hz1, ap);                                                 \
    at = MFMA16(A0, hE0, at);                                                 \
    at = MFMA16(A1, hE1, at);                                                 \
    TANHPACK(ap, at, HH, HD)                                                  \
  }

#define L2T(F, C, HHc, HDc)                                                   \
  {                                                                           \
    h4 A = s_w1[((F) * 8 + (C)) * 64 + lane];                                 \
    ap = MFMA16(A, HHc, ap);                                                  \
    at = MFMA16(A, HDc, at);                                                  \
  }

#define L2(F, GG, GD)                                                         \
  {                                                                           \
    f4 bb = *(const f4*)&s_bw[256 + (F) * 16 + g4];                           \
    f4 bt = *(const f4*)&s_bw[384 + (F) * 16 + g4];                           \
    f4 ap = bb + t * bt;                                                      \
    f4 at = {0.0f, 0.0f, 0.0f, 0.0f};                                         \
    L2T(F, 0, hh0, hd0) L2T(F, 1, hh1, hd1) L2T(F, 2, hh2, hd2)               \
    L2T(F, 3, hh3, hd3) L2T(F, 4, hh4, hd4) L2T(F, 5, hh5, hd5)               \
    L2T(F, 6, hh6, hd6) L2T(F, 7, hh7, hd7)                                   \
    TANHPACK(ap, at, GG, GD)                                                  \
  }

#define L3T(F, C, GGc, GDc)                                                   \
  {                                                                           \
    h4 A = s_w2[((F) * 8 + (C)) * 64 + lane];                                 \
    ap = MFMA16(A, GGc, ap);                                                  \
    at = MFMA16(A, GDc, at);                                                  \
  }

#define L3(F, KC, EH)                                                         \
  {                                                                           \
    f4 bb = *(const f4*)&s_bw[512 + (F) * 16 + g4];                           \
    f4 bt = *(const f4*)&s_bw[544 + (F) * 16 + g4];                           \
    f4 ap = bb + t * bt;                                                      \
    f4 at = {0.0f, 0.0f, 0.0f, 0.0f};                                         \
    L3T(F, 0, g10, gd0) L3T(F, 1, g11, gd1) L3T(F, 2, g12, gd2)               \
    L3T(F, 3, g13, gd3) L3T(F, 4, g14, gd4) L3T(F, 5, g15, gd5)               \
    L3T(F, 6, g16, gd6) L3T(F, 7, g17, gd7)                                   \
    KC = ap;                                                                  \
    lp += (EH).x * at.x + (EH).y * at.y + (EH).z * at.z + (EH).w * at.w;      \
  }

// ---------------- main kernel: 16 samples/wave, 4 waves/block --------------
__global__ __launch_bounds__(256, 2) void ffjord_kernel(
    const float* __restrict__ z1g, const float* __restrict__ epsg,
    const char* __restrict__ ws, float* __restrict__ out) {
  __shared__ h4 s_w0[1024];   // 8 KB
  __shared__ h4 s_w1[4096];   // 32 KB
  __shared__ h4 s_w2[1024];   // 8 KB
  __shared__ float s_bw[576]; // 2.25 KB

  {
    int tt = threadIdx.x;
    const f4* s0 = (const f4*)(ws);
    const f4* s1 = (const f4*)(ws + 8192);
    const f4* s2 = (const f4*)(ws + 40960);
    const f4* s3 = (const f4*)(ws + 49152);
    f4* d0 = (f4*)s_w0;
    f4* d1 = (f4*)s_w1;
    f4* d2 = (f4*)s_w2;
    f4* d3 = (f4*)s_bw;
#pragma unroll
    for (int i = 0; i < 2; i++) d0[tt + 256 * i] = s0[tt + 256 * i];
#pragma unroll
    for (int i = 0; i < 8; i++) d1[tt + 256 * i] = s1[tt + 256 * i];
#pragma unroll
    for (int i = 0; i < 2; i++) d2[tt + 256 * i] = s2[tt + 256 * i];
    if (tt < 144) d3[tt] = s3[tt];
  }
  __syncthreads();

  const int lane = threadIdx.x & 63;
  const int wv = threadIdx.x >> 6;
  const int sl = lane & 15;
  const int g4 = ((lane >> 4) << 2);
  const int sample = (blockIdx.x * 4 + wv) * 16 + sl;

  // per-lane state: features {c*16 + g4 + j}, c in {0,1}, j in 0..3
  f4 za, zb, ea, eb;
  {
    const f4* zp = (const f4*)(z1g + sample * 32);
    za = zp[g4 >> 2];
    zb = zp[(16 + g4) >> 2];
    const f4* ep = (const f4*)(epsg + sample * 32);
    ea = ep[g4 >> 2];
    eb = ep[(16 + g4) >> 2];
  }
  const h4 hE0 = {(_Float16)ea.x, (_Float16)ea.y, (_Float16)ea.z, (_Float16)ea.w};
  const h4 hE1 = {(_Float16)eb.x, (_Float16)eb.y, (_Float16)eb.z, (_Float16)eb.w};

  float ld = 0.0f;

  // RK4, reversed time: 5 steps, dt = -0.2
#pragma unroll 1
  for (int step = 0; step < 5; step++) {
    float t1 = 1.0f - 0.2f * (float)step;
    f4 kca = {0.0f, 0.0f, 0.0f, 0.0f}, kcb = {0.0f, 0.0f, 0.0f, 0.0f};
    f4 dka = {0.0f, 0.0f, 0.0f, 0.0f}, dkb = {0.0f, 0.0f, 0.0f, 0.0f};
    float dl = 0.0f;
#pragma unroll 1
    for (int st = 0; st < 4; st++) {
      // stage input scale == stage t offset: {0, -0.1, -0.1, -0.2}
      float isc = (st == 0) ? 0.0f : ((st == 3) ? -0.2f : -0.1f);
      float wg = (st == 1 || st == 2) ? 2.0f : 1.0f;
      float t = t1 + isc;
      h4 hz0 = {(_Float16)(za.x + isc * kca.x), (_Float16)(za.y + isc * kca.y),
                (_Float16)(za.z + isc * kca.z), (_Float16)(za.w + isc * kca.w)};
      h4 hz1 = {(_Float16)(zb.x + isc * kcb.x), (_Float16)(zb.y + isc * kcb.y),
                (_Float16)(zb.z + isc * kcb.z), (_Float16)(zb.w + isc * kcb.w)};

      // layer 1 (32 -> 128, tanh), primal + tangent
      h4 hh0, hh1, hh2, hh3, hh4, hh5, hh6, hh7;
      h4 hd0, hd1, hd2, hd3, hd4, hd5, hd6, hd7;
      L1(0, hh0, hd0) L1(1, hh1, hd1) L1(2, hh2, hd2) L1(3, hh3, hd3)
      L1(4, hh4, hd4) L1(5, hh5, hd5) L1(6, hh6, hd6) L1(7, hh7, hd7)

      // layer 2 (128 -> 128, tanh)
      h4 g10, g11, g12, g13, g14, g15, g16, g17;
      h4 gd0, gd1, gd2, gd3, gd4, gd5, gd6, gd7;
      L2(0, g10, gd0) L2(1, g11, gd1) L2(2, g12, gd2) L2(3, g13, gd3)
      L2(4, g14, gd4) L2(5, g15, gd5) L2(6, g16, gd6) L2(7, g17, gd7)

      // layer 3 (128 -> 32, linear) + Hutchinson partial
      float lp = 0.0f;
      L3(0, kca, ea)
      L3(1, kcb, eb)
      lp += __shfl_xor(lp, 16, 64);
      lp += __shfl_xor(lp, 32, 64);

      dka += wg * kca;
      dkb += wg * kcb;
      dl += wg * lp;
    }
    za += (-0.2f / 6.0f) * dka;
    zb += (-0.2f / 6.0f) * dkb;
    ld += (0.2f / 6.0f) * dl;   // ld -= dlogpz, dlogpz = dl*(dt/6), dt=-0.2
  }

  {
    f4* op = (f4*)(out + sample * 32);
    op[g4 >> 2] = za;
    op[(16 + g4) >> 2] = zb;
    if (lane < 16) out[131072 * 32 + sample] = ld;
  }
}

extern "C" void kernel_launch(void* const* d_in, const int* in_sizes, int n_in,
                              void* d_out, int out_size, void* d_ws, size_t ws_size,
                              hipStream_t stream) {
  (void)in_sizes; (void)n_in; (void)out_size; (void)ws_size;
  const float* z1 = (const float*)d_in[0];
  const float* eps = (const float*)d_in[1];
  const float* W0 = (const float*)d_in[2];
  const float* b0 = (const float*)d_in[3];
  const float* W1 = (const float*)d_in[4];
  const float* b1 = (const float*)d_in[5];
  const float* W2 = (const float*)d_in[6];
  const float* b2 = (const float*)d_in[7];
  float* out = (float*)d_out;

  prepack_kernel<<<16, 256, 0, stream>>>(W0, b0, W1, b1, W2, b2, (char*)d_ws);
  ffjord_kernel<<<131072 / 64, 256, 0, stream>>>(z1, eps, (const char*)d_ws, out);
}

// Round 5
// 402.300 us; speedup vs baseline: 5.5742x; 3.1737x over previous
//
#include <hip/hip_runtime.h>

// FFJORD CNF on MI355X. Transposed-MFMA design: every layer computed as
// H^T = W^T · X^T with v_mfma_f32_16x16x16_f16. For K=16 the C/D fragment
// layout (col=lane&15=sample, row=(lane>>4)*4+reg=feature) equals the
// B-operand layout, so layer outputs feed the next layer with only in-lane
// tanh + f32->f16 converts. Time column folded into bias: b_eff = b + t*W_row.
//
// R4 post-mortem: named registers fixed half the scratch (dur 2243->1277,
// VGPR 84->128) but 4.6 GB HBM remained: the pre-RA scheduler hoists A-frag
// ds_reads across feature blocks, ballooning live ranges -> allocator spills
// hh/hd. R5: __builtin_amdgcn_sched_barrier(0) between per-feature blocks
// bounds in-flight loads to one block's worth (8 ds_reads + 16 MFMAs).

typedef _Float16 h4 __attribute__((ext_vector_type(4)));
typedef float f4 __attribute__((ext_vector_type(4)));

#define MFMA16(A, B, C) __builtin_amdgcn_mfma_f32_16x16x16f16((A), (B), (C), 0, 0, 0)
#define SB() __builtin_amdgcn_sched_barrier(0)

__device__ __forceinline__ float fast_tanh(float x) {
  float e = __expf(2.0f * x);
  return 1.0f - 2.0f * __builtin_amdgcn_rcpf(e + 1.0f);
}

// ---------------- prepack: global weights -> MFMA fragment order in ws ----
// ws layout (bytes):
//   [0      .. 8192 )  w0 frags: 16 fragchunks x 64 lanes x h4   (8 KB)
//   [8192   .. 40960)  w1 frags: 64 fragchunks x 64 lanes x h4   (32 KB)
//   [40960  .. 49152)  w2 frags: 16 fragchunks x 64 lanes x h4   (8 KB)
//   [49152  .. 51456)  bias/time-row floats: bw[576]
//       bw[0:128]=b0  bw[128:256]=W0row32  bw[256:384]=b1 bw[384:512]=W1row128
//       bw[512:544]=b2 bw[544:576]=W2row128
__global__ void prepack_kernel(const float* __restrict__ W0, const float* __restrict__ b0,
                               const float* __restrict__ W1, const float* __restrict__ b1,
                               const float* __restrict__ W2, const float* __restrict__ b2,
                               char* __restrict__ ws) {
  h4* w0f = (h4*)(ws);
  h4* w1f = (h4*)(ws + 8192);
  h4* w2f = (h4*)(ws + 40960);
  float* bw = (float*)(ws + 49152);
  int tid = blockIdx.x * blockDim.x + threadIdx.x;
  int np = gridDim.x * blockDim.x;
  // A-fragment: A[m=f*16+(lane&15)][k=c*16+(lane>>4)*4+j] = W^T[m][k] = W[k][m]
  for (int e = tid; e < 1024; e += np) {
    int fc = e >> 6, lane = e & 63;
    int row = (fc >> 1) * 16 + (lane & 15);   // output feature (0..127)
    int kb = (fc & 1) * 16 + ((lane >> 4) << 2);
    h4 v;
#pragma unroll
    for (int j = 0; j < 4; j++) v[j] = (_Float16)W0[(kb + j) * 128 + row];
    w0f[e] = v;
  }
  for (int e = tid; e < 4096; e += np) {
    int fc = e >> 6, lane = e & 63;
    int row = (fc >> 3) * 16 + (lane & 15);
    int kb = (fc & 7) * 16 + ((lane >> 4) << 2);
    h4 v;
#pragma unroll
    for (int j = 0; j < 4; j++) v[j] = (_Float16)W1[(kb + j) * 128 + row];
    w1f[e] = v;
  }
  for (int e = tid; e < 1024; e += np) {
    int fc = e >> 6, lane = e & 63;
    int row = (fc >> 3) * 16 + (lane & 15);   // output feature (0..31)
    int kb = (fc & 7) * 16 + ((lane >> 4) << 2);
    h4 v;
#pragma unroll
    for (int j = 0; j < 4; j++) v[j] = (_Float16)W2[(kb + j) * 32 + row];
    w2f[e] = v;
  }
  for (int e = tid; e < 128; e += np) {
    bw[e] = b0[e];
    bw[128 + e] = W0[32 * 128 + e];
    bw[256 + e] = b1[e];
    bw[384 + e] = W1[128 * 128 + e];
  }
  for (int e = tid; e < 32; e += np) {
    bw[512 + e] = b2[e];
    bw[544 + e] = W2[128 * 32 + e];
  }
}

// ---- per-layer macros: all state in NAMED registers, offsets constant ----
#define TANHPACK(ap, at, HH, HD)                                              \
  {                                                                           \
    float th0 = fast_tanh((ap).x), th1 = fast_tanh((ap).y);                   \
    float th2 = fast_tanh((ap).z), th3 = fast_tanh((ap).w);                   \
    HH = (h4){(_Float16)th0, (_Float16)th1, (_Float16)th2, (_Float16)th3};    \
    HD = (h4){(_Float16)((1.0f - th0 * th0) * (at).x),                        \
              (_Float16)((1.0f - th1 * th1) * (at).y),                        \
              (_Float16)((1.0f - th2 * th2) * (at).z),                        \
              (_Float16)((1.0f - th3 * th3) * (at).w)};                       \
  }

#define L1(F, HH, HD)                                                         \
  {                                                                           \
    f4 bb = *(const f4*)&s_bw[(F) * 16 + g4];                                 \
    f4 bt = *(const f4*)&s_bw[128 + (F) * 16 + g4];                           \
    f4 ap = bb + t * bt;                                                      \
    f4 at = {0.0f, 0.0f, 0.0f, 0.0f};                                         \
    h4 A0 = s_w0[((F) * 2 + 0) * 64 + lane];                                  \
    h4 A1 = s_w0[((F) * 2 + 1) * 64 + lane];                                  \
    ap = MFMA16(A0, hz0, ap);                                                 \
    ap = MFMA16(A1, hz1, ap);                                                 \
    at = MFMA16(A0, hE0, at);                                                 \
    at = MFMA16(A1, hE1, at);                                                 \
    TANHPACK(ap, at, HH, HD)                                                  \
  }                                                                           \
  SB();

#define L2T(F, C, HHc, HDc)                                                   \
  {                                                                           \
    h4 A = s_w1[((F) * 8 + (C)) * 64 + lane];                                 \
    ap = MFMA16(A, HHc, ap);                                                  \
    at = MFMA16(A, HDc, at);                                                  \
  }

#define L2(F, GG, GD)                                                         \
  {                                                                           \
    f4 bb = *(const f4*)&s_bw[256 + (F) * 16 + g4];                           \
    f4 bt = *(const f4*)&s_bw[384 + (F) * 16 + g4];                           \
    f4 ap = bb + t * bt;                                                      \
    f4 at = {0.0f, 0.0f, 0.0f, 0.0f};                                         \
    L2T(F, 0, hh0, hd0) L2T(F, 1, hh1, hd1) L2T(F, 2, hh2, hd2)               \
    L2T(F, 3, hh3, hd3) L2T(F, 4, hh4, hd4) L2T(F, 5, hh5, hd5)               \
    L2T(F, 6, hh6, hd6) L2T(F, 7, hh7, hd7)                                   \
    TANHPACK(ap, at, GG, GD)                                                  \
  }                                                                           \
  SB();

#define L3T(F, C, GGc, GDc)                                                   \
  {                                                                           \
    h4 A = s_w2[((F) * 8 + (C)) * 64 + lane];                                 \
    ap = MFMA16(A, GGc, ap);                                                  \
    at = MFMA16(A, GDc, at);                                                  \
  }

#define L3(F, KC, EH)                                                         \
  {                                                                           \
    f4 bb = *(const f4*)&s_bw[512 + (F) * 16 + g4];                           \
    f4 bt = *(const f4*)&s_bw[544 + (F) * 16 + g4];                           \
    f4 ap = bb + t * bt;                                                      \
    f4 at = {0.0f, 0.0f, 0.0f, 0.0f};                                         \
    L3T(F, 0, g10, gd0) L3T(F, 1, g11, gd1) L3T(F, 2, g12, gd2)               \
    L3T(F, 3, g13, gd3) L3T(F, 4, g14, gd4) L3T(F, 5, g15, gd5)               \
    L3T(F, 6, g16, gd6) L3T(F, 7, g17, gd7)                                   \
    KC = ap;                                                                  \
    lp += (EH).x * at.x + (EH).y * at.y + (EH).z * at.z + (EH).w * at.w;      \
  }                                                                           \
  SB();

// ---------------- main kernel: 16 samples/wave, 4 waves/block --------------
__global__ __launch_bounds__(256, 2) void ffjord_kernel(
    const float* __restrict__ z1g, const float* __restrict__ epsg,
    const char* __restrict__ ws, float* __restrict__ out) {
  __shared__ h4 s_w0[1024];   // 8 KB
  __shared__ h4 s_w1[4096];   // 32 KB
  __shared__ h4 s_w2[1024];   // 8 KB
  __shared__ float s_bw[576]; // 2.25 KB

  {
    int tt = threadIdx.x;
    const f4* s0 = (const f4*)(ws);
    const f4* s1 = (const f4*)(ws + 8192);
    const f4* s2 = (const f4*)(ws + 40960);
    const f4* s3 = (const f4*)(ws + 49152);
    f4* d0 = (f4*)s_w0;
    f4* d1 = (f4*)s_w1;
    f4* d2 = (f4*)s_w2;
    f4* d3 = (f4*)s_bw;
#pragma unroll
    for (int i = 0; i < 2; i++) d0[tt + 256 * i] = s0[tt + 256 * i];
#pragma unroll
    for (int i = 0; i < 8; i++) d1[tt + 256 * i] = s1[tt + 256 * i];
#pragma unroll
    for (int i = 0; i < 2; i++) d2[tt + 256 * i] = s2[tt + 256 * i];
    if (tt < 144) d3[tt] = s3[tt];
  }
  __syncthreads();

  const int lane = threadIdx.x & 63;
  const int wv = threadIdx.x >> 6;
  const int sl = lane & 15;
  const int g4 = ((lane >> 4) << 2);
  const int sample = (blockIdx.x * 4 + wv) * 16 + sl;

  // per-lane state: features {c*16 + g4 + j}, c in {0,1}, j in 0..3
  f4 za, zb, ea, eb;
  {
    const f4* zp = (const f4*)(z1g + sample * 32);
    za = zp[g4 >> 2];
    zb = zp[(16 + g4) >> 2];
    const f4* ep = (const f4*)(epsg + sample * 32);
    ea = ep[g4 >> 2];
    eb = ep[(16 + g4) >> 2];
  }
  const h4 hE0 = {(_Float16)ea.x, (_Float16)ea.y, (_Float16)ea.z, (_Float16)ea.w};
  const h4 hE1 = {(_Float16)eb.x, (_Float16)eb.y, (_Float16)eb.z, (_Float16)eb.w};

  float ld = 0.0f;

  // RK4, reversed time: 5 steps, dt = -0.2
#pragma unroll 1
  for (int step = 0; step < 5; step++) {
    float t1 = 1.0f - 0.2f * (float)step;
    f4 kca = {0.0f, 0.0f, 0.0f, 0.0f}, kcb = {0.0f, 0.0f, 0.0f, 0.0f};
    f4 dka = {0.0f, 0.0f, 0.0f, 0.0f}, dkb = {0.0f, 0.0f, 0.0f, 0.0f};
    float dl = 0.0f;
#pragma unroll 1
    for (int st = 0; st < 4; st++) {
      // stage input scale == stage t offset: {0, -0.1, -0.1, -0.2}
      float isc = (st == 0) ? 0.0f : ((st == 3) ? -0.2f : -0.1f);
      float wg = (st == 1 || st == 2) ? 2.0f : 1.0f;
      float t = t1 + isc;
      h4 hz0 = {(_Float16)(za.x + isc * kca.x), (_Float16)(za.y + isc * kca.y),
                (_Float16)(za.z + isc * kca.z), (_Float16)(za.w + isc * kca.w)};
      h4 hz1 = {(_Float16)(zb.x + isc * kcb.x), (_Float16)(zb.y + isc * kcb.y),
                (_Float16)(zb.z + isc * kcb.z), (_Float16)(zb.w + isc * kcb.w)};
      SB();

      // layer 1 (32 -> 128, tanh), primal + tangent
      h4 hh0, hh1, hh2, hh3, hh4, hh5, hh6, hh7;
      h4 hd0, hd1, hd2, hd3, hd4, hd5, hd6, hd7;
      L1(0, hh0, hd0) L1(1, hh1, hd1) L1(2, hh2, hd2) L1(3, hh3, hd3)
      L1(4, hh4, hd4) L1(5, hh5, hd5) L1(6, hh6, hd6) L1(7, hh7, hd7)

      // layer 2 (128 -> 128, tanh)
      h4 g10, g11, g12, g13, g14, g15, g16, g17;
      h4 gd0, gd1, gd2, gd3, gd4, gd5, gd6, gd7;
      L2(0, g10, gd0) L2(1, g11, gd1) L2(2, g12, gd2) L2(3, g13, gd3)
      L2(4, g14, gd4) L2(5, g15, gd5) L2(6, g16, gd6) L2(7, g17, gd7)

      // layer 3 (128 -> 32, linear) + Hutchinson partial
      float lp = 0.0f;
      L3(0, kca, ea)
      L3(1, kcb, eb)
      lp += __shfl_xor(lp, 16, 64);
      lp += __shfl_xor(lp, 32, 64);

      dka += wg * kca;
      dkb += wg * kcb;
      dl += wg * lp;
    }
    za += (-0.2f / 6.0f) * dka;
    zb += (-0.2f / 6.0f) * dkb;
    ld += (0.2f / 6.0f) * dl;   // ld -= dlogpz, dlogpz = dl*(dt/6), dt=-0.2
  }

  {
    f4* op = (f4*)(out + sample * 32);
    op[g4 >> 2] = za;
    op[(16 + g4) >> 2] = zb;
    if (lane < 16) out[131072 * 32 + sample] = ld;
  }
}

extern "C" void kernel_launch(void* const* d_in, const int* in_sizes, int n_in,
                              void* d_out, int out_size, void* d_ws, size_t ws_size,
                              hipStream_t stream) {
  (void)in_sizes; (void)n_in; (void)out_size; (void)ws_size;
  const float* z1 = (const float*)d_in[0];
  const float* eps = (const float*)d_in[1];
  const float* W0 = (const float*)d_in[2];
  const float* b0 = (const float*)d_in[3];
  const float* W1 = (const float*)d_in[4];
  const float* b1 = (const float*)d_in[5];
  const float* W2 = (const float*)d_in[6];
  const float* b2 = (const float*)d_in[7];
  float* out = (float*)d_out;

  prepack_kernel<<<16, 256, 0, stream>>>(W0, b0, W1, b1, W2, b2, (char*)d_ws);
  ffjord_kernel<<<131072 / 64, 256, 0, stream>>>(z1, eps, (const char*)d_ws, out);
}